// Round 2
// baseline (929.892 us; speedup 1.0000x reference)
//
#include <hip/hip_runtime.h>

#define N_NODES 100000
#define N_EDGES 3200000
#define DIM 256

typedef short short8 __attribute__((ext_vector_type(8)));
typedef float f32x4 __attribute__((ext_vector_type(4)));

static __device__ __forceinline__ unsigned short f2bf(float f) {
    unsigned int u = __float_as_uint(f);
    u = (u + 0x7FFFu + ((u >> 16) & 1u)) >> 16;   // RNE
    return (unsigned short)u;
}
static __device__ __forceinline__ float bf2f(unsigned short s) {
    return __uint_as_float(((unsigned int)s) << 16);
}

// ---------------- CSR build ----------------
__global__ void k_hist(const int* __restrict__ row, int* __restrict__ cnt) {
    int e = blockIdx.x * 256 + threadIdx.x;
    atomicAdd(&cnt[row[e]], 1);
}

__global__ void k_scan1(const int* __restrict__ cnt, int* __restrict__ rs,
                        int* __restrict__ bsum) {
    __shared__ int lds[1024];
    int t = threadIdx.x;
    int g = blockIdx.x * 1024 + t;
    int x = cnt[g];
    lds[t] = x;
    __syncthreads();
    for (int off = 1; off < 1024; off <<= 1) {
        int v = (t >= off) ? lds[t - off] : 0;
        __syncthreads();
        lds[t] += v;
        __syncthreads();
    }
    rs[g] = lds[t] - x;                 // exclusive
    if (t == 1023) bsum[blockIdx.x] = lds[t];
}

__global__ void k_scan2(int* __restrict__ bsum) {   // 1 block, 128 thr, 98 valid
    __shared__ int lds[128];
    int t = threadIdx.x;
    int x = (t < 98) ? bsum[t] : 0;
    lds[t] = x;
    __syncthreads();
    for (int off = 1; off < 128; off <<= 1) {
        int v = (t >= off) ? lds[t - off] : 0;
        __syncthreads();
        lds[t] += v;
        __syncthreads();
    }
    if (t < 98) bsum[t] = lds[t] - x;   // exclusive
}

__global__ void k_scanadd(int* __restrict__ rs, const int* __restrict__ bsum,
                          int* __restrict__ cur) {
    int g = blockIdx.x * 1024 + threadIdx.x;
    int v = rs[g] + bsum[blockIdx.x];
    rs[g] = v;
    cur[g] = v;
}

__global__ void k_scatter(const int* __restrict__ row, const int* __restrict__ col,
                          const float* __restrict__ val, int* __restrict__ cur,
                          int2* __restrict__ csr) {
    int e = blockIdx.x * 256 + threadIdx.x;
    int r = row[e];
    int p = atomicAdd(&cur[r], 1);
    csr[p] = make_int2(col[e], __float_as_int(val[e]));
}

// ---------------- W pack (fp32 -> bf16 B-fragment layout) ----------------
// wp[((kc*16+nt)*64+lane)*8 + j] = bf16( W[(kc*32 + (lane>>4)*8 + j)*256 + nt*16 + (lane&15)] )
__global__ void k_wpack(const float* __restrict__ W, unsigned short* __restrict__ wp) {
    int t = blockIdx.x * 256 + threadIdx.x;     // 0..8191
    int lane = t & 63;
    int nt = (t >> 6) & 15;
    int kc = t >> 10;
    int n = nt * 16 + (lane & 15);
    int kbase = kc * 32 + ((lane >> 4) << 3);
    unsigned short* dst = wp + (size_t)t * 8;
#pragma unroll
    for (int j = 0; j < 8; j++) dst[j] = f2bf(W[(size_t)(kbase + j) * DIM + n]);
}

// ---------------- GEMM: support(bf16) = X @ W ----------------
__global__ __launch_bounds__(256, 1) void k_gemm(const float* __restrict__ X,
                                                 const unsigned short* __restrict__ wp,
                                                 unsigned short* __restrict__ sup) {
    __shared__ unsigned short wlds[65536];      // 128 KiB: full packed W
    int t = threadIdx.x;
    // coalesced 16B copy of packed W into LDS: 65536 shorts = 8192 uint4
    for (int i = t; i < 8192; i += 256)
        ((uint4*)wlds)[i] = ((const uint4*)wp)[i];
    __syncthreads();

    int wave = t >> 6, lane = t & 63;
    const int nstrips = (N_NODES + 127) / 128;  // 782
    for (int s = blockIdx.x; s < nstrips; s += gridDim.x) {
        int rowbase = s * 128 + wave * 32;
        f32x4 acc[2][16];
#pragma unroll
        for (int rb = 0; rb < 2; rb++)
#pragma unroll
            for (int nt = 0; nt < 16; nt++) acc[rb][nt] = (f32x4){0.f, 0.f, 0.f, 0.f};

        for (int kc = 0; kc < 8; kc++) {
            short8 afrag[2];
#pragma unroll
            for (int rb = 0; rb < 2; rb++) {
                int r = rowbase + rb * 16 + (lane & 15);
                short8 a = (short8)0;
                if (r < N_NODES) {
                    const float* ap = X + (size_t)r * DIM + kc * 32 + ((lane >> 4) << 3);
                    float4 a0 = *(const float4*)ap;
                    float4 a1 = *(const float4*)(ap + 4);
                    a[0] = (short)f2bf(a0.x); a[1] = (short)f2bf(a0.y);
                    a[2] = (short)f2bf(a0.z); a[3] = (short)f2bf(a0.w);
                    a[4] = (short)f2bf(a1.x); a[5] = (short)f2bf(a1.y);
                    a[6] = (short)f2bf(a1.z); a[7] = (short)f2bf(a1.w);
                }
                afrag[rb] = a;
            }
#pragma unroll
            for (int nt = 0; nt < 16; nt++) {
                short8 b = *(const short8*)&wlds[(size_t)(((kc * 16 + nt) * 64) + lane) * 8];
                acc[0][nt] = __builtin_amdgcn_mfma_f32_16x16x32_bf16(afrag[0], b, acc[0][nt], 0, 0, 0);
                acc[1][nt] = __builtin_amdgcn_mfma_f32_16x16x32_bf16(afrag[1], b, acc[1][nt], 0, 0, 0);
            }
        }
        // store: C/D layout col=lane&15, row=(lane>>4)*4+reg
#pragma unroll
        for (int rb = 0; rb < 2; rb++) {
            int rbase = rowbase + rb * 16 + ((lane >> 4) << 2);
#pragma unroll
            for (int rg = 0; rg < 4; rg++) {
                int r = rbase + rg;
                if (r < N_NODES) {
                    unsigned short* op = sup + (size_t)r * DIM + (lane & 15);
#pragma unroll
                    for (int nt = 0; nt < 16; nt++) op[nt * 16] = f2bf(acc[rb][nt][rg]);
                }
            }
        }
    }
}

// ---------------- CSR aggregation: one wave per row ----------------
__global__ __launch_bounds__(256) void k_agg(const int* __restrict__ rs,
                                             const int2* __restrict__ csr,
                                             const unsigned short* __restrict__ sup,
                                             const float* __restrict__ bias,
                                             float* __restrict__ out) {
    int wave = threadIdx.x >> 6, lane = threadIdx.x & 63;
    int r = blockIdx.x * 4 + wave;
    int s = rs[r], e = rs[r + 1];
    int d0 = lane * 4;
    float a0 = 0.f, a1 = 0.f, a2 = 0.f, a3 = 0.f;
    for (int i = s; i < e; ++i) {
        int2 ce = csr[i];
        float v = __int_as_float(ce.y);
        const unsigned short* sp = sup + (size_t)ce.x * DIM + d0;
        ushort4 u = *(const ushort4*)sp;
        a0 += v * bf2f(u.x);
        a1 += v * bf2f(u.y);
        a2 += v * bf2f(u.z);
        a3 += v * bf2f(u.w);
    }
    float4 b = *(const float4*)(bias + d0);
    float4 o;
    o.x = a0 + b.x; o.y = a1 + b.y; o.z = a2 + b.z; o.w = a3 + b.w;
    *(float4*)(out + (size_t)r * DIM + d0) = o;
}

extern "C" void kernel_launch(void* const* d_in, const int* in_sizes, int n_in,
                              void* d_out, int out_size, void* d_ws, size_t ws_size,
                              hipStream_t stream) {
    const float* X    = (const float*)d_in[0];
    const int*   erow = (const int*)d_in[1];
    const int*   ecol = (const int*)d_in[2];
    const float* eval = (const float*)d_in[3];
    const float* W    = (const float*)d_in[4];
    const float* bias = (const float*)d_in[5];
    float* out = (float*)d_out;

    char* ws = (char*)d_ws;
    int*            rsb  = (int*)ws;                          // 102400 ints
    int*            cur  = (int*)(ws + 409600);               // 102400 ints (also histogram)
    int*            bsum = (int*)(ws + 819200);               // 1024 ints
    unsigned short* wp   = (unsigned short*)(ws + 823296);    // 65536 bf16
    int2*           csr  = (int2*)(ws + 954368);              // 3.2M int2
    unsigned short* sup  = (unsigned short*)(ws + 26554368);  // 25.6M bf16
    // total ws use: 77,754,368 B

    hipMemsetAsync(cur, 0, 409600, stream);
    k_hist<<<N_EDGES / 256, 256, 0, stream>>>(erow, cur);
    k_scan1<<<98, 1024, 0, stream>>>(cur, rsb, bsum);
    k_scan2<<<1, 128, 0, stream>>>(bsum);
    k_scanadd<<<98, 1024, 0, stream>>>(rsb, bsum, cur);
    k_scatter<<<N_EDGES / 256, 256, 0, stream>>>(erow, ecol, eval, cur, csr);
    k_wpack<<<32, 256, 0, stream>>>(W, wp);
    k_gemm<<<256, 256, 0, stream>>>(X, wp, sup);
    k_agg<<<N_NODES / 4, 256, 0, stream>>>(rsb, csr, sup, bias, out);
}